// Round 4
// baseline (280.594 us; speedup 1.0000x reference)
//
#include <hip/hip_runtime.h>

#define TTOK 4096
#define NEXP 8
#define DDIM 512
#define FDIM 2048

typedef __attribute__((ext_vector_type(8))) short short8;
typedef __attribute__((ext_vector_type(4))) float floatx4;

__device__ __forceinline__ ushort f2b(float f) {
  unsigned u = __float_as_uint(f);
  u += 0x7fffu + ((u >> 16) & 1u);   // round-to-nearest-even bf16
  return (ushort)(u >> 16);
}

__device__ __forceinline__ void load16(void* lds, const void* g) {
  __builtin_amdgcn_global_load_lds(
      (const __attribute__((address_space(1))) unsigned int*)g,
      (__attribute__((address_space(3))) unsigned int*)lds, 16, 0, 0);
}

// ---------------- f32 -> bf16 convert for the 3 weight tensors in one launch
__global__ __launch_bounds__(256) void k_cvt3(
    const float* __restrict__ s1, ushort* __restrict__ d1,
    const float* __restrict__ s2, ushort* __restrict__ d2,
    const float* __restrict__ s3, ushort* __restrict__ d3, int n4)
{
  int i = blockIdx.x * 256 + threadIdx.x;
  const float* s; ushort* d; int j;
  if (i < n4)            { s = s1; d = d1; j = i; }
  else if (i < 2 * n4)   { s = s2; d = d2; j = i - n4; }
  else                   { s = s3; d = d3; j = i - 2 * n4; }
  float4 v = ((const float4*)s)[j];
  ushort4 b = { f2b(v.x), f2b(v.y), f2b(v.z), f2b(v.w) };
  ((ushort4*)d)[j] = b;
}

// ---------------- router pass 1: logits + top-2 + bf16 x out (NO atomics)
__global__ __launch_bounds__(256) void k_logits(
    const float* __restrict__ x, const float* __restrict__ gw,
    float* __restrict__ logits, int* __restrict__ tok_e,
    float2* __restrict__ tok_w, ushort* __restrict__ xb)
{
  const int lane = threadIdx.x & 63;
  const int t = blockIdx.x * 4 + (threadIdx.x >> 6);
  float xv[8];
#pragma unroll
  for (int i = 0; i < 8; ++i) xv[i] = x[(size_t)t * DDIM + lane + 64 * i];
#pragma unroll
  for (int i = 0; i < 8; ++i) xb[(size_t)t * DDIM + lane + 64 * i] = f2b(xv[i]);
  float lg[8];
#pragma unroll
  for (int e = 0; e < 8; ++e) {
    float a = 0.f;
#pragma unroll
    for (int i = 0; i < 8; ++i) a += xv[i] * gw[e * DDIM + lane + 64 * i];
#pragma unroll
    for (int s = 32; s; s >>= 1) a += __shfl_xor(a, s, 64);
    lg[e] = a;
  }
  if (lane < 8) logits[(size_t)t * 8 + lane] = lg[lane];
  if (lane == 0) {
    // top-2, ties -> lower index (matches jax.lax.top_k)
    int i0 = 0; float v0 = lg[0];
#pragma unroll
    for (int e = 1; e < 8; ++e) { if (lg[e] > v0) { v0 = lg[e]; i0 = e; } }
    int i1 = -1; float v1 = -3.4e38f;
#pragma unroll
    for (int e = 0; e < 8; ++e) { if (e != i0 && lg[e] > v1) { v1 = lg[e]; i1 = e; } }
    float ex = expf(v1 - v0);            // v1 <= v0, no overflow
    float inv = 1.f / (1.f + ex);
    tok_e[t] = i0 | (i1 << 4);
    tok_w[t] = make_float2(inv, ex * inv);
  }
}

// ---------------- router pass 2: per-expert compaction, ballot prefix, no atomics
__global__ __launch_bounds__(256) void k_build(
    const int* __restrict__ tok_e, const float2* __restrict__ tok_w,
    int* __restrict__ counts, int* __restrict__ lists, float* __restrict__ wts)
{
  const int e = blockIdx.x;
  const int tid = threadIdx.x;
  const int lane = tid & 63, wid = tid >> 6;
  __shared__ int wcnt[4];
  __shared__ int sbase;
  if (tid == 0) sbase = 0;
  __syncthreads();

  for (int c = 0; c < TTOK; c += 256) {
    int t = c + tid;
    int pe = tok_e[t];
    bool m0 = (pe & 15) == e;
    bool m1 = ((pe >> 4) & 15) == e;
    bool m = m0 || m1;
    unsigned long long b = __ballot(m);
    int lpre = __popcll(b & ((1ull << lane) - 1ull));
    if (lane == 0) wcnt[wid] = __popcll(b);
    __syncthreads();
    int woff = 0;
#pragma unroll
    for (int i = 0; i < 4; ++i) if (i < wid) woff += wcnt[i];
    if (m) {
      float2 w = tok_w[t];
      int pos = sbase + woff + lpre;
      lists[e * TTOK + pos] = t;
      wts[e * TTOK + pos] = m0 ? w.x : w.y;
    }
    __syncthreads();
    if (tid == 0) sbase += wcnt[0] + wcnt[1] + wcnt[2] + wcnt[3];
    __syncthreads();
  }
  if (tid == 0) counts[e] = sbase;
}

__global__ void k_offsets(const int* __restrict__ counts, int* __restrict__ offs) {
  if (threadIdx.x == 0 && blockIdx.x == 0) {
    int s = 0;
    for (int e = 0; e < NEXP; ++e) { offs[e] = s; s += counts[e]; }
  }
}

// ---------------- GEMM1: H = silu(X W1^T) * (X W3^T)
// A (gathered X rows) in registers from global; W1/W3 double-buffered in LDS.
__global__ __launch_bounds__(512) void k_ffn1(
    const ushort* __restrict__ xb, const ushort* __restrict__ w1b,
    const ushort* __restrict__ w3b, const int* __restrict__ counts,
    const int* __restrict__ offs, const int* __restrict__ lists,
    ushort* __restrict__ H)
{
  const int e = blockIdx.z;
  const int ne = counts[e];
  const int m0 = blockIdx.y * 128;
  if (m0 >= ne) return;
  const int f0 = blockIdx.x * 128;
  const int tid = threadIdx.x;

  __shared__ ushort w1s[2][128][64];
  __shared__ ushort w3s[2][128][64];
  __shared__ int toks[128];

  if (tid < 128) {
    int p = m0 + tid;
    toks[tid] = (p < ne) ? lists[e * TTOK + p] : 0;
  }

  const int wid = tid >> 6, lane = tid & 63;
  const int wm = wid >> 2, wn = wid & 3;     // 2 x 4 wave grid
  const int lr = lane & 15, lgp = lane >> 4;

  // staging geometry (per tensor, 2 loads/thread): idx=tid (+512), row=idx>>3, col=(idx&7)*8
  const int rA = tid >> 3, cA = (tid & 7) << 3;
  const int rB = (tid + 512) >> 3, cB = (tid & 7) << 3;
  const size_t wroff = (size_t)e * FDIM * DDIM + (size_t)f0 * DDIM;

  const ushort* w1A = w1b + wroff + (size_t)rA * DDIM + cA;
  const ushort* w1B = w1b + wroff + (size_t)rB * DDIM + cB;
  const ushort* w3A = w3b + wroff + (size_t)rA * DDIM + cA;
  const ushort* w3B = w3b + wroff + (size_t)rB * DDIM + cB;

#define FFN1_STAGE(NXT)                                                    \
  {                                                                        \
    char* d1 = (char*)&w1s[NXT][0][0] + wid * 1024;                        \
    char* d3 = (char*)&w3s[NXT][0][0] + wid * 1024;                        \
    load16(d1, w1A); load16(d1 + 8192, w1B);                               \
    load16(d3, w3A); load16(d3 + 8192, w3B);                               \
    w1A += 64; w1B += 64; w3A += 64; w3B += 64;                            \
  }

  floatx4 acc1[4][2], acc3[4][2];
#pragma unroll
  for (int a = 0; a < 4; ++a)
#pragma unroll
    for (int b = 0; b < 2; ++b) { acc1[a][b] = (floatx4)0.f; acc3[a][b] = (floatx4)0.f; }

  FFN1_STAGE(0);
  __syncthreads();   // toks visible + buf0 staged (drain)

  // A-row base pointers (gathered), per-lane
  const ushort* aptr[4];
#pragma unroll
  for (int mf = 0; mf < 4; ++mf)
    aptr[mf] = xb + (size_t)toks[wm * 64 + mf * 16 + lr] * DDIM + lgp * 8;

#define FFN1_COMPUTE(CUR)                                                  \
  {                                                                        \
    short8 a0[4], a1[4];                                                   \
    _Pragma("unroll")                                                      \
    for (int mf = 0; mf < 4; ++mf) {                                       \
      a0[mf] = *(const short8*)(aptr[mf] + k0);                            \
      a1[mf] = *(const short8*)(aptr[mf] + k0 + 32);                       \
    }                                                                      \
    _Pragma("unroll")                                                      \
    for (int kk = 0; kk < 2; ++kk) {                                       \
      short8 f1[2], f3[2];                                                 \
      _Pragma("unroll")                                                    \
      for (int nf = 0; nf < 2; ++nf) {                                     \
        f1[nf] = *(const short8*)&w1s[CUR][wn * 32 + nf * 16 + lr][kk * 32 + lgp * 8]; \
        f3[nf] = *(const short8*)&w3s[CUR][wn * 32 + nf * 16 + lr][kk * 32 + lgp * 8]; \
      }                                                                    \
      _Pragma("unroll")                                                    \
      for (int mf = 0; mf < 4; ++mf)                                       \
        _Pragma("unroll")                                                  \
        for (int nf = 0; nf < 2; ++nf) {                                   \
          acc1[mf][nf] = __builtin_amdgcn_mfma_f32_16x16x32_bf16(          \
              kk ? a1[mf] : a0[mf], f1[nf], acc1[mf][nf], 0, 0, 0);        \
          acc3[mf][nf] = __builtin_amdgcn_mfma_f32_16x16x32_bf16(          \
              kk ? a1[mf] : a0[mf], f3[nf], acc3[mf][nf], 0, 0, 0);        \
        }                                                                  \
    }                                                                      \
  }

  int k0 = 0;
  for (int t = 0; t < 8; t += 2) {
    if (t + 1 < 8) FFN1_STAGE(1);
    FFN1_COMPUTE(0);
    k0 += 64;
    __syncthreads();
    if (t + 2 < 8) FFN1_STAGE(0);
    FFN1_COMPUTE(1);
    k0 += 64;
    __syncthreads();
  }

  const int hb = offs[e];
#pragma unroll
  for (int mf = 0; mf < 4; ++mf) {
#pragma unroll
    for (int j = 0; j < 4; ++j) {
      int rloc = wm * 64 + mf * 16 + lgp * 4 + j;   // C/D: row=(l>>4)*4+j
      int p = m0 + rloc;
      if (p < ne) {
#pragma unroll
        for (int nf = 0; nf < 2; ++nf) {
          float h1 = acc1[mf][nf][j];
          float h3 = acc3[mf][nf][j];
          float sig = 1.f / (1.f + __expf(-h1));
          int f = f0 + wn * 32 + nf * 16 + lr;      // C/D: col=l&15
          H[(size_t)(hb + p) * FDIM + f] = f2b(h1 * sig * h3);
        }
      }
    }
  }
#undef FFN1_STAGE
#undef FFN1_COMPUTE
}

// ---------------- GEMM2: Y = H W2^T, scaled atomic scatter into out
// A (compact H rows) in registers from global; W2 double-buffered in LDS.
__global__ __launch_bounds__(512) void k_ffn2(
    const ushort* __restrict__ w2b, const int* __restrict__ counts,
    const int* __restrict__ offs, const int* __restrict__ lists,
    const float* __restrict__ wts, const ushort* __restrict__ H,
    float* __restrict__ out)
{
  const int e = blockIdx.z;
  const int ne = counts[e];
  const int m0 = blockIdx.y * 128;
  if (m0 >= ne) return;
  const int d0 = blockIdx.x * 128;
  const int tid = threadIdx.x;

  __shared__ ushort w2s[2][128][64];
  __shared__ int toks[128];
  __shared__ float twt[128];

  const int hb = offs[e];
  if (tid < 128) {
    int p = m0 + tid;
    bool v = p < ne;
    toks[tid] = v ? lists[e * TTOK + p] : 0;
    twt[tid] = v ? wts[e * TTOK + p] : 0.f;
  }

  const int wid = tid >> 6, lane = tid & 63;
  const int wm = wid >> 2, wn = wid & 3;
  const int lr = lane & 15, lgp = lane >> 4;

  const int rA = tid >> 3, cA = (tid & 7) << 3;
  const int rB = (tid + 512) >> 3, cB = (tid & 7) << 3;
  const size_t wroff = (size_t)e * DDIM * FDIM + (size_t)d0 * FDIM;

  const ushort* w2A = w2b + wroff + (size_t)rA * FDIM + cA;
  const ushort* w2B = w2b + wroff + (size_t)rB * FDIM + cB;

#define FFN2_STAGE(NXT)                                                    \
  {                                                                        \
    char* d2 = (char*)&w2s[NXT][0][0] + wid * 1024;                        \
    load16(d2, w2A); load16(d2 + 8192, w2B);                               \
    w2A += 64; w2B += 64;                                                  \
  }

  floatx4 acc[4][2];
#pragma unroll
  for (int a = 0; a < 4; ++a)
#pragma unroll
    for (int b = 0; b < 2; ++b) acc[a][b] = (floatx4)0.f;

  FFN2_STAGE(0);
  __syncthreads();

  // A-row pointers into compact H (clamped for tail rows)
  const ushort* hptr[4];
#pragma unroll
  for (int mf = 0; mf < 4; ++mf) {
    int p = m0 + wm * 64 + mf * 16 + lr;
    hptr[mf] = H + (size_t)(hb + ((p < ne) ? p : 0)) * FDIM + lgp * 8;
  }

#define FFN2_COMPUTE(CUR)                                                  \
  {                                                                        \
    short8 a0[4], a1[4];                                                   \
    _Pragma("unroll")                                                      \
    for (int mf = 0; mf < 4; ++mf) {                                       \
      a0[mf] = *(const short8*)(hptr[mf] + k0);                            \
      a1[mf] = *(const short8*)(hptr[mf] + k0 + 32);                       \
    }                                                                      \
    _Pragma("unroll")                                                      \
    for (int kk = 0; kk < 2; ++kk) {                                       \
      short8 bf[2];                                                        \
      _Pragma("unroll")                                                    \
      for (int nf = 0; nf < 2; ++nf)                                       \
        bf[nf] = *(const short8*)&w2s[CUR][wn * 32 + nf * 16 + lr][kk * 32 + lgp * 8]; \
      _Pragma("unroll")                                                    \
      for (int mf = 0; mf < 4; ++mf)                                       \
        _Pragma("unroll")                                                  \
        for (int nf = 0; nf < 2; ++nf)                                     \
          acc[mf][nf] = __builtin_amdgcn_mfma_f32_16x16x32_bf16(           \
              kk ? a1[mf] : a0[mf], bf[nf], acc[mf][nf], 0, 0, 0);         \
    }                                                                      \
  }

  int k0 = 0;
  for (int t = 0; t < 32; t += 2) {
    if (t + 1 < 32) FFN2_STAGE(1);
    FFN2_COMPUTE(0);
    k0 += 64;
    __syncthreads();
    if (t + 2 < 32) FFN2_STAGE(0);
    FFN2_COMPUTE(1);
    k0 += 64;
    __syncthreads();
  }

#pragma unroll
  for (int mf = 0; mf < 4; ++mf) {
#pragma unroll
    for (int j = 0; j < 4; ++j) {
      int rloc = wm * 64 + mf * 16 + lgp * 4 + j;
      int p = m0 + rloc;
      if (p < ne) {
        int t = toks[rloc];
        float w = twt[rloc];
#pragma unroll
        for (int nf = 0; nf < 2; ++nf) {
          int d = d0 + wn * 32 + nf * 16 + lr;
          atomicAdd(&out[(size_t)t * DDIM + d], w * acc[mf][nf][j]);
        }
      }
    }
  }
#undef FFN2_STAGE
#undef FFN2_COMPUTE
}

extern "C" void kernel_launch(void* const* d_in, const int* in_sizes, int n_in,
                              void* d_out, int out_size, void* d_ws, size_t ws_size,
                              hipStream_t stream) {
  const float* x  = (const float*)d_in[0];
  const float* gw = (const float*)d_in[1];
  const float* w1 = (const float*)d_in[2];
  const float* w2 = (const float*)d_in[3];
  const float* w3 = (const float*)d_in[4];
  float* out = (float*)d_out;
  float* logits = out + (size_t)TTOK * DDIM;

  // workspace layout (~88.3 MB)
  int* counts = (int*)d_ws;                       // [8]
  int* offs   = counts + 8;                       // [8]
  int* tok_e  = offs + 8;                         // [4096]
  float2* tok_w = (float2*)(tok_e + TTOK);        // [4096]
  int* lists  = (int*)(tok_w + TTOK);             // [8][4096]
  float* wts  = (float*)(lists + NEXP * TTOK);    // [8][4096]
  ushort* xbb = (ushort*)(wts + NEXP * TTOK);     // [4096][512]  bf16
  ushort* w1b = xbb + (size_t)TTOK * DDIM;        // [8][2048][512] bf16
  ushort* w3b = w1b + (size_t)NEXP * FDIM * DDIM;
  ushort* w2b = w3b + (size_t)NEXP * FDIM * DDIM; // [8][512][2048] bf16
  ushort* H   = w2b + (size_t)NEXP * DDIM * FDIM; // [8192][2048] bf16

  hipMemsetAsync(d_out, 0, (size_t)TTOK * DDIM * sizeof(float), stream);

  const int nW = NEXP * FDIM * DDIM / 4;          // 2,097,152
  k_logits<<<TTOK / 4, 256, 0, stream>>>(x, gw, logits, tok_e, tok_w, xbb);
  k_build<<<NEXP, 256, 0, stream>>>(tok_e, tok_w, counts, lists, wts);
  k_offsets<<<1, 64, 0, stream>>>(counts, offs);

  k_cvt3<<<3 * nW / 256, 256, 0, stream>>>(w1, w1b, w3, w3b, w2, w2b, nW);

  k_ffn1<<<dim3(FDIM / 128, TTOK / 128, NEXP), 512, 0, stream>>>(xbb, w1b, w3b, counts, offs, lists, H);
  k_ffn2<<<dim3(DDIM / 128, TTOK / 128, NEXP), 512, 0, stream>>>(w2b, counts, offs, lists, wts, H, out);
}

// Round 5
// 160.465 us; speedup vs baseline: 1.7486x; 1.7486x over previous
//
#include <hip/hip_runtime.h>

#define TTOK 4096
#define NEXP 8
#define DDIM 512
#define FDIM 2048

typedef __attribute__((ext_vector_type(8))) short short8;
typedef __attribute__((ext_vector_type(4))) float floatx4;

__device__ __forceinline__ ushort f2b(float f) {
  unsigned u = __float_as_uint(f);
  u += 0x7fffu + ((u >> 16) & 1u);   // round-to-nearest-even bf16
  return (ushort)(u >> 16);
}

__device__ __forceinline__ void load16(void* lds, const void* g) {
  __builtin_amdgcn_global_load_lds(
      (const __attribute__((address_space(1))) unsigned int*)g,
      (__attribute__((address_space(3))) unsigned int*)lds, 16, 0, 0);
}

// ---------------- f32 -> bf16 convert for the 3 weight tensors in one launch
__global__ __launch_bounds__(256) void k_cvt3(
    const float* __restrict__ s1, ushort* __restrict__ d1,
    const float* __restrict__ s2, ushort* __restrict__ d2,
    const float* __restrict__ s3, ushort* __restrict__ d3, int n4)
{
  int i = blockIdx.x * 256 + threadIdx.x;
  const float* s; ushort* d; int j;
  if (i < n4)            { s = s1; d = d1; j = i; }
  else if (i < 2 * n4)   { s = s2; d = d2; j = i - n4; }
  else                   { s = s3; d = d3; j = i - 2 * n4; }
  float4 v = ((const float4*)s)[j];
  ushort4 b = { f2b(v.x), f2b(v.y), f2b(v.z), f2b(v.w) };
  ((ushort4*)d)[j] = b;
}

// ---------------- router pass 1: logits + top-2 + bf16 x out (NO atomics)
__global__ __launch_bounds__(256) void k_logits(
    const float* __restrict__ x, const float* __restrict__ gw,
    float* __restrict__ logits, int* __restrict__ tok_e,
    float2* __restrict__ tok_w, ushort* __restrict__ xb)
{
  const int lane = threadIdx.x & 63;
  const int t = blockIdx.x * 4 + (threadIdx.x >> 6);
  float xv[8];
#pragma unroll
  for (int i = 0; i < 8; ++i) xv[i] = x[(size_t)t * DDIM + lane + 64 * i];
#pragma unroll
  for (int i = 0; i < 8; ++i) xb[(size_t)t * DDIM + lane + 64 * i] = f2b(xv[i]);
  float lg[8];
#pragma unroll
  for (int e = 0; e < 8; ++e) {
    float a = 0.f;
#pragma unroll
    for (int i = 0; i < 8; ++i) a += xv[i] * gw[e * DDIM + lane + 64 * i];
#pragma unroll
    for (int s = 32; s; s >>= 1) a += __shfl_xor(a, s, 64);
    lg[e] = a;
  }
  if (lane < 8) logits[(size_t)t * 8 + lane] = lg[lane];
  if (lane == 0) {
    // top-2, ties -> lower index (matches jax.lax.top_k)
    int i0 = 0; float v0 = lg[0];
#pragma unroll
    for (int e = 1; e < 8; ++e) { if (lg[e] > v0) { v0 = lg[e]; i0 = e; } }
    int i1 = -1; float v1 = -3.4e38f;
#pragma unroll
    for (int e = 0; e < 8; ++e) { if (e != i0 && lg[e] > v1) { v1 = lg[e]; i1 = e; } }
    float ex = expf(v1 - v0);            // v1 <= v0, no overflow
    float inv = 1.f / (1.f + ex);
    tok_e[t] = i0 | (i1 << 4);
    tok_w[t] = make_float2(inv, ex * inv);
  }
}

// ---------------- router pass 2: per-expert compaction, ballot prefix, no atomics
__global__ __launch_bounds__(256) void k_build(
    const int* __restrict__ tok_e, const float2* __restrict__ tok_w,
    int* __restrict__ counts, int* __restrict__ lists, float* __restrict__ wts)
{
  const int e = blockIdx.x;
  const int tid = threadIdx.x;
  const int lane = tid & 63, wid = tid >> 6;
  __shared__ int wcnt[4];
  __shared__ int sbase;
  if (tid == 0) sbase = 0;
  __syncthreads();

  for (int c = 0; c < TTOK; c += 256) {
    int t = c + tid;
    int pe = tok_e[t];
    bool m0 = (pe & 15) == e;
    bool m1 = ((pe >> 4) & 15) == e;
    bool m = m0 || m1;
    unsigned long long b = __ballot(m);
    int lpre = __popcll(b & ((1ull << lane) - 1ull));
    if (lane == 0) wcnt[wid] = __popcll(b);
    __syncthreads();
    int woff = 0;
#pragma unroll
    for (int i = 0; i < 4; ++i) if (i < wid) woff += wcnt[i];
    if (m) {
      float2 w = tok_w[t];
      int pos = sbase + woff + lpre;
      lists[e * TTOK + pos] = t;
      wts[e * TTOK + pos] = m0 ? w.x : w.y;
    }
    __syncthreads();
    if (tid == 0) sbase += wcnt[0] + wcnt[1] + wcnt[2] + wcnt[3];
    __syncthreads();
  }
  if (tid == 0) counts[e] = sbase;
}

__global__ void k_offsets(const int* __restrict__ counts, int* __restrict__ offs) {
  if (threadIdx.x == 0 && blockIdx.x == 0) {
    int s = 0;
    for (int e = 0; e < NEXP; ++e) { offs[e] = s; s += counts[e]; }
  }
}

// ---------------- GEMM1: H = silu(X W1^T) * (X W3^T)
// BK=32, [128][32] tiles (bank-uniform), dbuf, single barrier per K-step.
// 1D grid, XCD-chunked swizzle, work order: m innermost.
__global__ __launch_bounds__(512) void k_ffn1(
    const ushort* __restrict__ xb, const ushort* __restrict__ w1b,
    const ushort* __restrict__ w3b, const int* __restrict__ counts,
    const int* __restrict__ offs, const int* __restrict__ lists,
    ushort* __restrict__ H)
{
  // nwg = 32*8*16 = 4096, cpx = 512
  const int bid = blockIdx.x;
  const int widx = (bid & 7) * 512 + (bid >> 3);
  const int mt = widx & 31, e = (widx >> 5) & 7, f0t = widx >> 8;
  const int ne = counts[e];
  const int m0 = mt * 128;
  if (m0 >= ne) return;
  const int f0 = f0t * 128;
  const int tid = threadIdx.x;

  __shared__ ushort xs[2][128][32];
  __shared__ ushort w1s[2][128][32];
  __shared__ ushort w3s[2][128][32];
  __shared__ int toks[128];

  if (tid < 128) {
    int p = m0 + tid;
    toks[tid] = (p < ne) ? lists[e * TTOK + p] : 0;
  }
  __syncthreads();

  const int wid = tid >> 6, lane = tid & 63;
  const int wm = wid >> 2, wn = wid & 3;     // 2 x 4 wave grid
  const int lr = lane & 15, lgp = lane >> 4;

  // staging: 1 load16 per tensor per thread per K-step
  const int sr = tid >> 2, sc = (tid & 3) << 3;
  const ushort* xS  = xb + (size_t)toks[sr] * DDIM + sc;
  const ushort* w1S = w1b + (size_t)e * FDIM * DDIM + (size_t)(f0 + sr) * DDIM + sc;
  const ushort* w3S = w3b + (size_t)e * FDIM * DDIM + (size_t)(f0 + sr) * DDIM + sc;

#define FFN1_STAGE(B)                                                      \
  {                                                                        \
    load16((char*)&xs[B][0][0] + wid * 1024, xS);                          \
    load16((char*)&w1s[B][0][0] + wid * 1024, w1S);                        \
    load16((char*)&w3s[B][0][0] + wid * 1024, w3S);                        \
    xS += 32; w1S += 32; w3S += 32;                                        \
  }

#define FFN1_COMPUTE(B)                                                    \
  {                                                                        \
    short8 af[4], f1[2], f3[2];                                            \
    _Pragma("unroll")                                                      \
    for (int mf = 0; mf < 4; ++mf)                                         \
      af[mf] = *(const short8*)&xs[B][wm * 64 + mf * 16 + lr][lgp * 8];    \
    _Pragma("unroll")                                                      \
    for (int nf = 0; nf < 2; ++nf) {                                       \
      f1[nf] = *(const short8*)&w1s[B][wn * 32 + nf * 16 + lr][lgp * 8];   \
      f3[nf] = *(const short8*)&w3s[B][wn * 32 + nf * 16 + lr][lgp * 8];   \
    }                                                                      \
    _Pragma("unroll")                                                      \
    for (int mf = 0; mf < 4; ++mf)                                         \
      _Pragma("unroll")                                                    \
      for (int nf = 0; nf < 2; ++nf) {                                     \
        acc1[mf][nf] = __builtin_amdgcn_mfma_f32_16x16x32_bf16(            \
            af[mf], f1[nf], acc1[mf][nf], 0, 0, 0);                        \
        acc3[mf][nf] = __builtin_amdgcn_mfma_f32_16x16x32_bf16(            \
            af[mf], f3[nf], acc3[mf][nf], 0, 0, 0);                        \
      }                                                                    \
  }

  floatx4 acc1[4][2], acc3[4][2];
#pragma unroll
  for (int a = 0; a < 4; ++a)
#pragma unroll
    for (int b = 0; b < 2; ++b) { acc1[a][b] = (floatx4)0.f; acc3[a][b] = (floatx4)0.f; }

  FFN1_STAGE(0);
  __syncthreads();           // buf0 staged

  for (int t = 0; t < 16; t += 2) {      // K = 512 / 32
    if (t + 1 < 16) FFN1_STAGE(1);
    FFN1_COMPUTE(0);
    __syncthreads();
    if (t + 2 < 16) FFN1_STAGE(0);
    FFN1_COMPUTE(1);
    __syncthreads();
  }

  const int hb = offs[e];
#pragma unroll
  for (int mf = 0; mf < 4; ++mf) {
#pragma unroll
    for (int j = 0; j < 4; ++j) {
      int rloc = wm * 64 + mf * 16 + lgp * 4 + j;   // C/D: row=(l>>4)*4+j
      int p = m0 + rloc;
      if (p < ne) {
#pragma unroll
        for (int nf = 0; nf < 2; ++nf) {
          float h1 = acc1[mf][nf][j];
          float h3 = acc3[mf][nf][j];
          float sig = 1.f / (1.f + __expf(-h1));
          int f = f0 + wn * 32 + nf * 16 + lr;      // C/D: col=l&15
          H[(size_t)(hb + p) * FDIM + f] = f2b(h1 * sig * h3);
        }
      }
    }
  }
#undef FFN1_STAGE
#undef FFN1_COMPUTE
}

// ---------------- GEMM2: Y = H W2^T, scaled atomic scatter into out
// BK=64 staged as 2x [128][32] half-tiles, dbuf, single barrier per K-step.
__global__ __launch_bounds__(512) void k_ffn2(
    const ushort* __restrict__ w2b, const int* __restrict__ counts,
    const int* __restrict__ offs, const int* __restrict__ lists,
    const float* __restrict__ wts, const ushort* __restrict__ H,
    float* __restrict__ out)
{
  // nwg = 32*8*4 = 1024, cpx = 128
  const int bid = blockIdx.x;
  const int widx = (bid & 7) * 128 + (bid >> 3);
  const int mt = widx & 31, e = (widx >> 5) & 7, d0t = widx >> 8;
  const int ne = counts[e];
  const int m0 = mt * 128;
  if (m0 >= ne) return;
  const int d0 = d0t * 128;
  const int tid = threadIdx.x;

  __shared__ ushort hs[2][2][128][32];
  __shared__ ushort w2s[2][2][128][32];
  __shared__ int toks[128];
  __shared__ float twt[128];

  const int hb = offs[e];
  if (tid < 128) {
    int p = m0 + tid;
    bool v = p < ne;
    toks[tid] = v ? lists[e * TTOK + p] : 0;
    twt[tid] = v ? wts[e * TTOK + p] : 0.f;
  }

  const int wid = tid >> 6, lane = tid & 63;
  const int wm = wid >> 2, wn = wid & 3;
  const int lr = lane & 15, lgp = lane >> 4;

  // staging: each thread loads row (tid>>2); half 0 at col sc, half 1 at col 32+sc
  const int sr = tid >> 2, sc = (tid & 3) << 3;
  const int p0 = m0 + sr;
  const int hr = (p0 < ne) ? (hb + p0) : hb;       // clamp to a valid row
  const ushort* hS  = H + (size_t)hr * FDIM + sc;
  const ushort* w2S = w2b + (size_t)e * DDIM * FDIM + (size_t)(d0 + sr) * FDIM + sc;

#define FFN2_STAGE(B)                                                      \
  {                                                                        \
    load16((char*)&hs[B][0][0][0] + wid * 1024, hS);                       \
    load16((char*)&hs[B][1][0][0] + wid * 1024, hS + 32);                  \
    load16((char*)&w2s[B][0][0][0] + wid * 1024, w2S);                     \
    load16((char*)&w2s[B][1][0][0] + wid * 1024, w2S + 32);                \
    hS += 64; w2S += 64;                                                   \
  }

#define FFN2_COMPUTE(B)                                                    \
  {                                                                        \
    _Pragma("unroll")                                                      \
    for (int kk = 0; kk < 2; ++kk) {                                       \
      short8 af[4], bf[2];                                                 \
      _Pragma("unroll")                                                    \
      for (int mf = 0; mf < 4; ++mf)                                       \
        af[mf] = *(const short8*)&hs[B][kk][wm * 64 + mf * 16 + lr][lgp * 8]; \
      _Pragma("unroll")                                                    \
      for (int nf = 0; nf < 2; ++nf)                                       \
        bf[nf] = *(const short8*)&w2s[B][kk][wn * 32 + nf * 16 + lr][lgp * 8]; \
      _Pragma("unroll")                                                    \
      for (int mf = 0; mf < 4; ++mf)                                       \
        _Pragma("unroll")                                                  \
        for (int nf = 0; nf < 2; ++nf)                                     \
          acc[mf][nf] = __builtin_amdgcn_mfma_f32_16x16x32_bf16(           \
              af[mf], bf[nf], acc[mf][nf], 0, 0, 0);                       \
    }                                                                      \
  }

  floatx4 acc[4][2];
#pragma unroll
  for (int a = 0; a < 4; ++a)
#pragma unroll
    for (int b = 0; b < 2; ++b) acc[a][b] = (floatx4)0.f;

  FFN2_STAGE(0);
  __syncthreads();

  for (int t = 0; t < 32; t += 2) {      // K = 2048 / 64
    if (t + 1 < 32) FFN2_STAGE(1);
    FFN2_COMPUTE(0);
    __syncthreads();
    if (t + 2 < 32) FFN2_STAGE(0);
    FFN2_COMPUTE(1);
    __syncthreads();
  }

#pragma unroll
  for (int mf = 0; mf < 4; ++mf) {
#pragma unroll
    for (int j = 0; j < 4; ++j) {
      int rloc = wm * 64 + mf * 16 + lgp * 4 + j;
      int p = m0 + rloc;
      if (p < ne) {
        int t = toks[rloc];
        float w = twt[rloc];
#pragma unroll
        for (int nf = 0; nf < 2; ++nf) {
          int d = d0 + wn * 32 + nf * 16 + lr;
          atomicAdd(&out[(size_t)t * DDIM + d], w * acc[mf][nf][j]);
        }
      }
    }
  }
#undef FFN2_STAGE
#undef FFN2_COMPUTE
}

extern "C" void kernel_launch(void* const* d_in, const int* in_sizes, int n_in,
                              void* d_out, int out_size, void* d_ws, size_t ws_size,
                              hipStream_t stream) {
  const float* x  = (const float*)d_in[0];
  const float* gw = (const float*)d_in[1];
  const float* w1 = (const float*)d_in[2];
  const float* w2 = (const float*)d_in[3];
  const float* w3 = (const float*)d_in[4];
  float* out = (float*)d_out;
  float* logits = out + (size_t)TTOK * DDIM;

  // workspace layout (~88.3 MB)
  int* counts = (int*)d_ws;                       // [8]
  int* offs   = counts + 8;                       // [8]
  int* tok_e  = offs + 8;                         // [4096]
  float2* tok_w = (float2*)(tok_e + TTOK);        // [4096]
  int* lists  = (int*)(tok_w + TTOK);             // [8][4096]
  float* wts  = (float*)(lists + NEXP * TTOK);    // [8][4096]
  ushort* xbb = (ushort*)(wts + NEXP * TTOK);     // [4096][512]  bf16
  ushort* w1b = xbb + (size_t)TTOK * DDIM;        // [8][2048][512] bf16
  ushort* w3b = w1b + (size_t)NEXP * FDIM * DDIM;
  ushort* w2b = w3b + (size_t)NEXP * FDIM * DDIM; // [8][512][2048] bf16
  ushort* H   = w2b + (size_t)NEXP * DDIM * FDIM; // [8192][2048] bf16

  hipMemsetAsync(d_out, 0, (size_t)TTOK * DDIM * sizeof(float), stream);

  const int nW = NEXP * FDIM * DDIM / 4;          // 2,097,152
  k_logits<<<TTOK / 4, 256, 0, stream>>>(x, gw, logits, tok_e, tok_w, xbb);
  k_build<<<NEXP, 256, 0, stream>>>(tok_e, tok_w, counts, lists, wts);
  k_offsets<<<1, 64, 0, stream>>>(counts, offs);

  k_cvt3<<<3 * nW / 256, 256, 0, stream>>>(w1, w1b, w3, w3b, w2, w2b, nW);

  k_ffn1<<<4096, 512, 0, stream>>>(xbb, w1b, w3b, counts, offs, lists, H);
  k_ffn2<<<1024, 512, 0, stream>>>(w2b, counts, offs, lists, wts, H, out);
}